// Round 11
// baseline (138.100 us; speedup 1.0000x reference)
//
#include <hip/hip_runtime.h>
#include <hip/hip_bf16.h>
#include <cstddef>
#include <cstdint>

// Problem constants (B=2, L=4096, C=512, H=8, K=64, D=64)
// max_window = 12, half_max = 6, S = 13, max_offset = 12.0, hid = 128

typedef _Float16 f16x8 __attribute__((ext_vector_type(8)));
typedef float f32x4 __attribute__((ext_vector_type(4)));

#define AS1 __attribute__((address_space(1)))
#define AS3 __attribute__((address_space(3)))

__device__ __forceinline__ void gload_lds16(const ushort* g, ushort* l) {
  __builtin_amdgcn_global_load_lds((const AS1 uint32_t*)g, (AS3 uint32_t*)l, 16, 0, 0);
}
__device__ __forceinline__ ushort f2h(float x) {
  _Float16 h = (_Float16)x;
  return __builtin_bit_cast(ushort, h);
}
__device__ __forceinline__ float h2f(ushort u) {
  return (float)__builtin_bit_cast(_Float16, u);
}
__device__ __forceinline__ float readlane_f(float v, int l) {
  return __int_as_float(__builtin_amdgcn_readlane(__float_as_int(v), l));
}
__device__ __forceinline__ float sigm(float z) { return 1.f / (1.f + __expf(-z)); }

// ---------------------------------------------------------------------------
// fp16 MFMA GEMM: C[m,n] = sum_k A[m,k] * B[n,k]   (K=512)
// 128x128 tile, BK=64, 4 waves (2x2), 4x4 frags of 16x16x32, XOR-swizzled LDS.
// 1D grid + XCD-chunked swizzle.
// MODE 0: 512 blocks, N=1024 -> cols <512 to fp16 Ck (+bk), >=512 to Cv (+bv);
//         A and B both staged via global_load_lds.
// MODE 1: 256 blocks, N=512; A reg-staged with per-k fp16 scale
//         (scale_h[b*512+k], b = m0>>12); B = out_w fp16 (batch-shared);
//         epilogue silu -> fp32 Cf.
// ---------------------------------------------------------------------------
template<int MODE>
__global__ __launch_bounds__(256, 2) void gemm_mfma(
    const ushort* __restrict__ A, const ushort* __restrict__ B,
    const float* __restrict__ bk, const float* __restrict__ bv,
    ushort* __restrict__ Ck, ushort* __restrict__ Cv,
    float* __restrict__ Cf, const ushort* __restrict__ scale_h)
{
  __shared__ ushort smem[2 * 8192];   // A tile 128x64 | B tile 128x64 (fp16)
  const int t = threadIdx.x, wid = t >> 6, l = t & 63;

  const int bid = blockIdx.x;
  const int xcd = bid & 7, idx = bid >> 3;
  const int bx = (xcd << 3) | (idx & 7);
  const int by = idx >> 3;
  const int m0 = bx * 128, n0 = by * 128;

  // staging addresses; global col-block pre-swizzled by row&7
  const int swz = ((t & 7) ^ ((t >> 3) & 7)) * 8;
  const ushort* gsrc[8];      // MODE0: 8 gloads; MODE1: [4..7] = B gloads
  const ushort* asrc[4];      // MODE1 reg-staged A
  const ushort* sptr = nullptr;
  uint32_t loff[8];
#pragma unroll
  for (int i = 0; i < 4; i++) {
    loff[i]     = (i * 32 + wid * 8) * 64;           // wave-uniform
    loff[4 + i] = 8192 + (i * 32 + wid * 8) * 64;
    if (MODE == 0) gsrc[i] = A + (size_t)(m0 + i * 32 + (t >> 3)) * 512 + swz;
    else           asrc[i] = A + (size_t)(m0 + i * 32 + (t >> 3)) * 512 + swz;
    gsrc[4 + i] = B + (size_t)(n0 + i * 32 + (t >> 3)) * 512 + swz;
  }
  if (MODE == 1) sptr = scale_h + (size_t)(m0 >> 12) * 512 + swz;
  const uint32_t awr = (uint32_t)((t >> 3) * 64 + (t & 7) * 8);  // per-thread A dst

  f32x4 acc[4][4];
#pragma unroll
  for (int m = 0; m < 4; m++)
#pragma unroll
    for (int n = 0; n < 4; n++) acc[m][n] = (f32x4){0.f, 0.f, 0.f, 0.f};

  const int wr = wid >> 1, wc = wid & 1;
  const int fr = l & 15, fq = l >> 4;

  for (int k0 = 0; k0 < 512; k0 += 64) {
    if constexpr (MODE == 1) {
      f16x8 sv = *(const f16x8*)sptr; sptr += 64;
#pragma unroll
      for (int i = 0; i < 4; i++) {
        f16x8 av = *(const f16x8*)asrc[i]; asrc[i] += 64;
        f16x8 pv = av * sv;                          // v_pk_mul_f16
        *(f16x8*)&smem[i * 32 * 64 + awr] = pv;
      }
#pragma unroll
      for (int i = 0; i < 4; i++) {
        gload_lds16(gsrc[4 + i], &smem[loff[4 + i]]);
        gsrc[4 + i] += 64;
      }
    } else {
#pragma unroll
      for (int j = 0; j < 8; j++) {
        gload_lds16(gsrc[j], &smem[loff[j]]);
        gsrc[j] += 64;
      }
    }
    __syncthreads();   // tiles resident (drains vmcnt + lgkmcnt)

    f16x8 af[4][2], bf[4][2];
#pragma unroll
    for (int m = 0; m < 4; m++)
#pragma unroll
      for (int ks = 0; ks < 2; ks++) {
        const int ko = 8 * ((ks * 4 + fq) ^ (fr & 7));   // read-side XOR
        af[m][ks] = *(const f16x8*)&smem[(wr * 64 + m * 16 + fr) * 64 + ko];
        bf[m][ks] = *(const f16x8*)&smem[8192 + (wc * 64 + m * 16 + fr) * 64 + ko];
      }
#pragma unroll
    for (int ks = 0; ks < 2; ks++)
#pragma unroll
      for (int m = 0; m < 4; m++)
#pragma unroll
        for (int n = 0; n < 4; n++)
          acc[m][n] = __builtin_amdgcn_mfma_f32_16x16x32_f16(af[m][ks], bf[n][ks], acc[m][n], 0, 0, 0);
    __syncthreads();   // reads done before next stage overwrites
  }

  // epilogue: C/D layout col=lane&15, row=(lane>>4)*4+reg
  const int rbase = m0 + wr * 64 + (l >> 4) * 4;
  const int cbase = n0 + wc * 64 + (l & 15);
#pragma unroll
  for (int m = 0; m < 4; m++)
#pragma unroll
    for (int n = 0; n < 4; n++) {
      const int c = cbase + n * 16;
#pragma unroll
      for (int j = 0; j < 4; j++) {
        const int r = rbase + m * 16 + j;
        float v = acc[m][n][j];
        if (MODE == 0) {
          if (n0 < 512) Ck[(size_t)r * 512 + c]         = f2h(v + bk[c]);
          else          Cv[(size_t)r * 512 + (c - 512)] = f2h(v + bv[c - 512]);
        } else {
          Cf[(size_t)r * 512 + c] = v * sigm(v);
        }
      }
    }
}

// ---------------------------------------------------------------------------
// window / offset projection + rmsnorm(H=8) + sigmoid/tanh + x fp16 copy.
// Blocks 512..639: fp16 conversion of kernel_w | v_w | out_w; zero counter.
// ---------------------------------------------------------------------------
__global__ __launch_bounds__(256) void winoff_kernel(
    const float* __restrict__ x,
    const float* __restrict__ window_w, const float* __restrict__ window_b,
    const float* __restrict__ window_g,
    const float* __restrict__ offset_w, const float* __restrict__ offset_b,
    const float* __restrict__ offset_g,
    float* __restrict__ halfwin, float* __restrict__ cenoff,
    ushort* __restrict__ xh,
    const float* __restrict__ kernel_w, const float* __restrict__ v_w,
    const float* __restrict__ out_w,
    ushort* __restrict__ wkv_h, ushort* __restrict__ ow16,
    uint* __restrict__ counter)
{
  const int t = threadIdx.x;
  if (blockIdx.x >= 512) {           // weight conversion side-job
    if (blockIdx.x == 512 && t == 0) *counter = 0u;
    for (int i = (blockIdx.x - 512) * 256 + t; i < 196608; i += 32768) {
      float4 v;
      if (i < 65536)       v = ((const float4*)kernel_w)[i];
      else if (i < 131072) v = ((const float4*)v_w)[i - 65536];
      else                 v = ((const float4*)out_w)[i - 131072];
      ushort4 o = {f2h(v.x), f2h(v.y), f2h(v.z), f2h(v.w)};
      if (i < 131072) ((ushort4*)wkv_h)[i] = o;
      else            ((ushort4*)ow16)[i - 131072] = o;
    }
    return;
  }
  __shared__ float wsm[16][512];   // rows 0..7 window_w, 8..15 offset_w
  {
    float4* dst = (float4*)&wsm[0][0];
    for (int i = t; i < 2048; i += 256)
      dst[i] = (i < 1024) ? ((const float4*)window_w)[i] : ((const float4*)offset_w)[i - 1024];
  }
  __syncthreads();
  const int wid = t >> 6, lane = t & 63;
  for (int it = 0; it < 4; it++) {
    const int row = blockIdx.x * 16 + it * 4 + wid;
    const float4* xr4 = (const float4*)(x + (size_t)row * 512);
    float4 a0 = xr4[lane * 2], a1 = xr4[lane * 2 + 1];
    ushort4 h0 = {f2h(a0.x), f2h(a0.y), f2h(a0.z), f2h(a0.w)};
    ushort4 h1 = {f2h(a1.x), f2h(a1.y), f2h(a1.z), f2h(a1.w)};
    ((ushort4*)(xh + (size_t)row * 512))[lane * 2]     = h0;
    ((ushort4*)(xh + (size_t)row * 512))[lane * 2 + 1] = h1;
    float s[16];
#pragma unroll
    for (int n = 0; n < 16; n++) {
      const float4* wr = (const float4*)&wsm[n][0];
      float4 w0 = wr[lane * 2], w1 = wr[lane * 2 + 1];
      float p = a0.x * w0.x + a0.y * w0.y + a0.z * w0.z + a0.w * w0.w
              + a1.x * w1.x + a1.y * w1.y + a1.z * w1.z + a1.w * w1.w;
#pragma unroll
      for (int off = 32; off >= 1; off >>= 1) p += __shfl_xor(p, off);
      s[n] = p;
    }
    float ssw = 0.f, sso = 0.f;
#pragma unroll
    for (int h = 0; h < 8; h++) {
      s[h]     += window_b[h]; ssw += s[h] * s[h];
      s[8 + h] += offset_b[h]; sso += s[8 + h] * s[8 + h];
    }
    float rw = rsqrtf(ssw * 0.125f + 1e-6f);
    float ro = rsqrtf(sso * 0.125f + 1e-6f);
    if (lane < 8) {
      float z = window_g[lane] * s[lane] * rw;
      halfwin[(size_t)row * 8 + lane] = fmaxf((1.0f + sigm(z) * 11.0f) * 0.5f, 0.5f);
    } else if (lane < 16) {
      int h = lane - 8;
      float z = offset_g[h] * s[8 + h] * ro;
      float th = 1.f - 2.f / (__expf(2.f * z) + 1.f);
      cenoff[(size_t)row * 8 + h] = th * 12.0f;
    }
  }
}

// ---------------------------------------------------------------------------
// fused rmsnorm+silu + deformable conv: one block = one row (512 thr, 8 waves)
// wave w = head h, lane = d. kn in registers; kn[idx] via __shfl; single
// barrier. Interior rows: bilinear collapses, 14 unconditional batched loads.
// XCD-chunked row swizzle (XCD x owns rows [x*1024, x*1024+1024)).
// ---------------------------------------------------------------------------
__global__ __launch_bounds__(512) void conv_row_kernel(
    const float* __restrict__ halfwin, const float* __restrict__ cenoff,
    const ushort* __restrict__ kact_h, const float* __restrict__ kernel_g,
    const ushort* __restrict__ v_h, ushort* __restrict__ oh_h)
{
  __shared__ float red[8];
  const int bid = blockIdx.x;                       // 8192
  const int row = ((bid & 7) << 10) | (bid >> 3);   // 1024 rows per XCD chunk
  const int t = threadIdx.x, w = t >> 6, lane = t & 63;
  const int b = row >> 12, l = row & 4095;

  // rmsnorm partial (this wave's 64-slice) + cross-wave combine
  float kraw = h2f(kact_h[(size_t)row * 512 + t]);
  float ss = kraw * kraw;
#pragma unroll
  for (int off = 32; off >= 1; off >>= 1) ss += __shfl_xor(ss, off);
  if (lane == 0) red[w] = ss;
  __syncthreads();
  float tot = red[0] + red[1] + red[2] + red[3]
            + red[4] + red[5] + red[6] + red[7];
  float r = rsqrtf(tot * (1.f / 512.f) + 1e-6f);
  float a = kernel_g[t] * kraw * r;
  float kn_l = a * sigm(a);              // this lane's kn[d], head w

  const int gw = row * 8 + w;
  const float hw = halfwin[gw];
  const float co = cenoff[gw];
  const ushort* vbase = v_h + ((size_t)b * 4096) * 512 + w * 64 + lane;

  // weight phase: all lanes compute; only lanes 0..12 meaningful
  const float soff = (float)(lane - 6);
  float rel  = fabsf(soff) / hw;
  float ww   = __expf(-rel * rel);
  float npos = fminf(rel, 1.f) * 63.f;
  int   idxk = min((int)npos, 62);
  float wc   = npos - (float)idxk;
  float kf = __shfl(kn_l, idxk);
  float kc = __shfl(kn_l, idxk + 1);
  float kw = fmaxf(kf * (1.f - wc) + kc * wc, 0.f);
  float nb = (float)l + co + soff;
  float wgt = (lane < 13 && nb >= 0.f && nb < 4096.f) ? (kw + 1.f) * ww : 0.f;
  float pc  = fminf(fmaxf(nb, 0.f), 4094.999f);
  int   pfv = (int)pc;
  float frv = pc - (float)pfv;

  float wsum = wgt;
#pragma unroll
  for (int off = 32; off >= 1; off >>= 1) wsum += __shfl_xor(wsum, off);

  const int base = __builtin_amdgcn_readlane(pfv, 0);
  const bool ok = (lane >= 13) || (pfv == base + lane);
  const bool fast = __all((int)ok) && (base + 13 <= 4095);

  float acc0 = 0.f, acc1 = 0.f;
  if (fast) {
    // collapse bilinear: u[r] = w_r*(1-fr_r) + w_{r-1}*fr_{r-1}
    float wfr = wgt * frv;
    float w1f = wgt - wfr;
    float up  = __shfl_up(wfr, 1);
    float u = (lane < 13 ? w1f : 0.f) + ((lane >= 1 && lane <= 13) ? up : 0.f);
    const ushort* vr = vbase + (size_t)base * 512;
    float xv[14];
#pragma unroll
    for (int rr = 0; rr < 14; rr++) xv[rr] = h2f(vr[(size_t)rr * 512]);
#pragma unroll
    for (int rr = 0; rr < 14; rr += 2) {
      acc0 = fmaf(readlane_f(u, rr),     xv[rr],     acc0);
      acc1 = fmaf(readlane_f(u, rr + 1), xv[rr + 1], acc1);
    }
  } else {
#pragma unroll
    for (int si = 0; si < 13; si++) {
      const float w_s  = readlane_f(wgt, si);
      const float fr_s = readlane_f(frv, si);
      const int   pf_s = __builtin_amdgcn_readlane(pfv, si);
      const int   pcl  = min(pf_s + 1, 4095);
      float v0 = h2f(vbase[(size_t)pf_s * 512]);
      float v1 = h2f(vbase[(size_t)pcl * 512]);
      acc0 = fmaf(w_s, v0 + fr_s * (v1 - v0), acc0);
    }
  }

  float val = (acc0 + acc1) / fmaxf(wsum, 1.f);
  oh_h[(size_t)row * 512 + w * 64 + lane] = f2h(val);
}

// ---------------------------------------------------------------------------
// fused SE: 128 XCD-local colpart blocks; the LAST block (agent-scope atomic
// counter) computes mean -> hid = silu(mean@w1^T) -> scale_h = f16(sigmoid
// (hid@w2^T)). Release via ACQ_REL fetch_add; winoff zeroes counter.
// ---------------------------------------------------------------------------
__global__ __launch_bounds__(256) void se_fused_kernel(
    const ushort* __restrict__ oh_h,
    const float* __restrict__ w1, const float* __restrict__ w2,
    float* __restrict__ partial, ushort* __restrict__ scale_h,
    uint* __restrict__ counter)
{
  const int blk = blockIdx.x;               // 128
  const int g = (blk & 7) * 16 + (blk >> 3);  // XCD-local 64-row chunk
  const int t = threadIdx.x;
  {
    const size_t base = (size_t)g * 64 * 512;
    float s0 = 0.f, s1 = 0.f;
#pragma unroll 8
    for (int i = 0; i < 64; i++) {
      uint u = *(const uint*)(oh_h + base + (size_t)i * 512 + t * 2);
      s0 += h2f((ushort)(u & 0xffffu));
      s1 += h2f((ushort)(u >> 16));
    }
    partial[(size_t)g * 512 + t * 2]     = s0;
    partial[(size_t)g * 512 + t * 2 + 1] = s1;
  }

  __shared__ uint is_last;
  __syncthreads();                          // all block stores drained (vmcnt)
  if (t == 0) {
    uint prev = __hip_atomic_fetch_add(counter, 1u, __ATOMIC_ACQ_REL,
                                       __HIP_MEMORY_SCOPE_AGENT);
    is_last = (prev == 127u) ? 1u : 0u;
  }
  __syncthreads();
  if (!is_last) return;

  // --- last block: mean -> hid -> scale ---
  __shared__ float mean_s[2][512];
  __shared__ float hid_s[2][128];
#pragma unroll
  for (int rp = 0; rp < 4; rp++) {
    const int idx2 = t + rp * 256;          // 0..1023
    const int b = idx2 >> 9, c = idx2 & 511;
    float m = 0.f;
#pragma unroll 8
    for (int ch = 0; ch < 64; ch++)
      m += partial[(size_t)(b * 64 + ch) * 512 + c];
    mean_s[b][c] = m * (1.f / 4096.f);
  }
  __syncthreads();
  {
    const int b = t >> 7, j = t & 127;      // 256 hidden units
    const float4* mr = (const float4*)&mean_s[b][0];
    const float4* wr = (const float4*)(w1 + (size_t)j * 512);
    float ac[4] = {0.f, 0.f, 0.f, 0.f};
#pragma unroll
    for (int q = 0; q < 128; q++) {
      float4 wv = wr[q], mv = mr[q];
      ac[q & 3] += wv.x * mv.x + wv.y * mv.y + wv.z * mv.z + wv.w * mv.w;
    }
    float p = ac[0] + ac[1] + ac[2] + ac[3];
    hid_s[b][j] = p * sigm(p);
  }
  __syncthreads();
#pragma unroll
  for (int rp = 0; rp < 4; rp++) {
    const int idx2 = t + rp * 256;          // 0..1023
    const int b = idx2 >> 9, c = idx2 & 511;
    const float4* hr = (const float4*)&hid_s[b][0];
    const float4* wr = (const float4*)(w2 + (size_t)c * 128);
    float p = 0.f;
#pragma unroll
    for (int q = 0; q < 32; q++) {
      float4 wv = wr[q], hv = hr[q];
      p += wv.x * hv.x + wv.y * hv.y + wv.z * hv.z + wv.w * hv.w;
    }
    scale_h[idx2] = f2h(sigm(p));
  }
}

// ---------------------------------------------------------------------------
extern "C" void kernel_launch(void* const* d_in, const int* in_sizes, int n_in,
                              void* d_out, int out_size, void* d_ws, size_t ws_size,
                              hipStream_t stream) {
  const float* x        = (const float*)d_in[0];
  const float* window_w = (const float*)d_in[1];
  const float* window_b = (const float*)d_in[2];
  const float* window_g = (const float*)d_in[3];
  const float* offset_w = (const float*)d_in[4];
  const float* offset_b = (const float*)d_in[5];
  const float* offset_g = (const float*)d_in[6];
  const float* kernel_w = (const float*)d_in[7];
  const float* kernel_b = (const float*)d_in[8];
  const float* kernel_g = (const float*)d_in[9];
  const float* v_w      = (const float*)d_in[10];
  const float* v_b      = (const float*)d_in[11];
  const float* se_w1    = (const float*)d_in[12];
  const float* se_w2    = (const float*)d_in[13];
  const float* out_w    = (const float*)d_in[14];
  float* out = (float*)d_out;
  char* ws   = (char*)d_ws;

  const size_t BLC = (size_t)8192 * 512;
  float* halfwin  = (float*)ws;                       ws += 65536 * 4;
  float* cenoff   = (float*)ws;                       ws += 65536 * 4;
  float* partial  = (float*)ws;                       ws += 128 * 512 * 4;
  uint*  counter  = (uint*)ws;                        ws += 64;
  ushort* scale_h = (ushort*)ws;                      ws += 1024 * 2;
  ushort* xh      = (ushort*)ws;                      ws += BLC * 2;
  ushort* wkv_h   = (ushort*)ws;                      ws += 1024 * 512 * 2;
  ushort* ow16    = (ushort*)ws;                      ws += 512 * 512 * 2;
  ushort* kact_h  = (ushort*)ws;                      ws += BLC * 2;
  ushort* v_h     = (ushort*)ws;                      ws += BLC * 2;
  ushort* oh_h    = (ushort*)ws;                      ws += BLC * 2;

  // 1. window/offset projection + x fp16 copy + weight fp16 conversions
  winoff_kernel<<<640, 256, 0, stream>>>(x, window_w, window_b, window_g,
                                         offset_w, offset_b, offset_g,
                                         halfwin, cenoff, xh,
                                         kernel_w, v_w, out_w,
                                         wkv_h, ow16, counter);
  // 2. kernel + v projections (fused dual fp16 MFMA GEMM over N=1024)
  gemm_mfma<0><<<512, 256, 0, stream>>>(xh, wkv_h, kernel_b, v_b,
                                        kact_h, v_h, nullptr, nullptr);
  // 3. fused rmsnorm+silu + deformable conv
  conv_row_kernel<<<8192, 512, 0, stream>>>(halfwin, cenoff, kact_h, kernel_g,
                                            v_h, oh_h);
  // 4. fused SE: colpart + (last block) mean/hid/scale -> scale_h fp16
  se_fused_kernel<<<128, 256, 0, stream>>>(oh_h, se_w1, se_w2,
                                           partial, scale_h, counter);
  // 5. final fp16 MFMA GEMM + silu (A = oh * scale via pk_mul, B = out_w fp16)
  gemm_mfma<1><<<256, 256, 0, stream>>>(oh_h, ow16, nullptr, nullptr,
                                        nullptr, nullptr, out, scale_h);
}

// Round 12
// 84.231 us; speedup vs baseline: 1.6395x; 1.6395x over previous
//
#include <hip/hip_runtime.h>
#include <hip/hip_bf16.h>
#include <cstddef>
#include <cstdint>

// Problem constants (B=2, L=4096, C=512, H=8, K=64, D=64)
// max_window = 12, half_max = 6, S = 13, max_offset = 12.0, hid = 128

typedef _Float16 f16x8 __attribute__((ext_vector_type(8)));
typedef float f32x4 __attribute__((ext_vector_type(4)));

#define AS1 __attribute__((address_space(1)))
#define AS3 __attribute__((address_space(3)))

__device__ __forceinline__ void gload_lds16(const ushort* g, ushort* l) {
  __builtin_amdgcn_global_load_lds((const AS1 uint32_t*)g, (AS3 uint32_t*)l, 16, 0, 0);
}
__device__ __forceinline__ ushort f2h(float x) {
  _Float16 h = (_Float16)x;
  return __builtin_bit_cast(ushort, h);
}
__device__ __forceinline__ float h2f(ushort u) {
  return (float)__builtin_bit_cast(_Float16, u);
}
__device__ __forceinline__ float readlane_f(float v, int l) {
  return __int_as_float(__builtin_amdgcn_readlane(__float_as_int(v), l));
}
__device__ __forceinline__ float sigm(float z) { return 1.f / (1.f + __expf(-z)); }

// ---------------------------------------------------------------------------
// fp16 MFMA GEMM: C[m,n] = sum_k A[m,k] * B[n,k]   (K=512)
// 128x128 tile, BK=64, 4 waves (2x2), 4x4 frags of 16x16x32, XOR-swizzled LDS.
// 1D grid + XCD-chunked swizzle.
// MODE 0: 512 blocks, N=1024 -> cols <512 to fp16 Ck (+bk), >=512 to Cv (+bv);
//         A and B both staged via global_load_lds.
// MODE 1: 256 blocks, N=512; A reg-staged with per-k fp16 scale
//         (scale_h[b*512+k], b = m0>>12); B = out_w fp16 (batch-shared);
//         epilogue silu -> fp32 Cf.
// ---------------------------------------------------------------------------
template<int MODE>
__global__ __launch_bounds__(256, 2) void gemm_mfma(
    const ushort* __restrict__ A, const ushort* __restrict__ B,
    const float* __restrict__ bk, const float* __restrict__ bv,
    ushort* __restrict__ Ck, ushort* __restrict__ Cv,
    float* __restrict__ Cf, const ushort* __restrict__ scale_h)
{
  __shared__ ushort smem[2 * 8192];   // A tile 128x64 | B tile 128x64 (fp16)
  const int t = threadIdx.x, wid = t >> 6, l = t & 63;

  const int bid = blockIdx.x;
  const int xcd = bid & 7, idx = bid >> 3;
  const int bx = (xcd << 3) | (idx & 7);
  const int by = idx >> 3;
  const int m0 = bx * 128, n0 = by * 128;

  // staging addresses; global col-block pre-swizzled by row&7
  const int swz = ((t & 7) ^ ((t >> 3) & 7)) * 8;
  const ushort* gsrc[8];      // MODE0: 8 gloads; MODE1: [4..7] = B gloads
  const ushort* asrc[4];      // MODE1 reg-staged A
  const ushort* sptr = nullptr;
  uint32_t loff[8];
#pragma unroll
  for (int i = 0; i < 4; i++) {
    loff[i]     = (i * 32 + wid * 8) * 64;           // wave-uniform
    loff[4 + i] = 8192 + (i * 32 + wid * 8) * 64;
    if (MODE == 0) gsrc[i] = A + (size_t)(m0 + i * 32 + (t >> 3)) * 512 + swz;
    else           asrc[i] = A + (size_t)(m0 + i * 32 + (t >> 3)) * 512 + swz;
    gsrc[4 + i] = B + (size_t)(n0 + i * 32 + (t >> 3)) * 512 + swz;
  }
  if (MODE == 1) sptr = scale_h + (size_t)(m0 >> 12) * 512 + swz;
  const uint32_t awr = (uint32_t)((t >> 3) * 64 + (t & 7) * 8);  // per-thread A dst

  f32x4 acc[4][4];
#pragma unroll
  for (int m = 0; m < 4; m++)
#pragma unroll
    for (int n = 0; n < 4; n++) acc[m][n] = (f32x4){0.f, 0.f, 0.f, 0.f};

  const int wr = wid >> 1, wc = wid & 1;
  const int fr = l & 15, fq = l >> 4;

  for (int k0 = 0; k0 < 512; k0 += 64) {
    if constexpr (MODE == 1) {
      f16x8 sv = *(const f16x8*)sptr; sptr += 64;
#pragma unroll
      for (int i = 0; i < 4; i++) {
        f16x8 av = *(const f16x8*)asrc[i]; asrc[i] += 64;
        f16x8 pv = av * sv;                          // v_pk_mul_f16
        *(f16x8*)&smem[i * 32 * 64 + awr] = pv;
      }
#pragma unroll
      for (int i = 0; i < 4; i++) {
        gload_lds16(gsrc[4 + i], &smem[loff[4 + i]]);
        gsrc[4 + i] += 64;
      }
    } else {
#pragma unroll
      for (int j = 0; j < 8; j++) {
        gload_lds16(gsrc[j], &smem[loff[j]]);
        gsrc[j] += 64;
      }
    }
    __syncthreads();   // tiles resident (drains vmcnt + lgkmcnt)

    f16x8 af[4][2], bf[4][2];
#pragma unroll
    for (int m = 0; m < 4; m++)
#pragma unroll
      for (int ks = 0; ks < 2; ks++) {
        const int ko = 8 * ((ks * 4 + fq) ^ (fr & 7));   // read-side XOR
        af[m][ks] = *(const f16x8*)&smem[(wr * 64 + m * 16 + fr) * 64 + ko];
        bf[m][ks] = *(const f16x8*)&smem[8192 + (wc * 64 + m * 16 + fr) * 64 + ko];
      }
#pragma unroll
    for (int ks = 0; ks < 2; ks++)
#pragma unroll
      for (int m = 0; m < 4; m++)
#pragma unroll
        for (int n = 0; n < 4; n++)
          acc[m][n] = __builtin_amdgcn_mfma_f32_16x16x32_f16(af[m][ks], bf[n][ks], acc[m][n], 0, 0, 0);
    __syncthreads();   // reads done before next stage overwrites
  }

  // epilogue: C/D layout col=lane&15, row=(lane>>4)*4+reg
  const int rbase = m0 + wr * 64 + (l >> 4) * 4;
  const int cbase = n0 + wc * 64 + (l & 15);
#pragma unroll
  for (int m = 0; m < 4; m++)
#pragma unroll
    for (int n = 0; n < 4; n++) {
      const int c = cbase + n * 16;
#pragma unroll
      for (int j = 0; j < 4; j++) {
        const int r = rbase + m * 16 + j;
        float v = acc[m][n][j];
        if (MODE == 0) {
          if (n0 < 512) Ck[(size_t)r * 512 + c]         = f2h(v + bk[c]);
          else          Cv[(size_t)r * 512 + (c - 512)] = f2h(v + bv[c - 512]);
        } else {
          Cf[(size_t)r * 512 + c] = v * sigm(v);
        }
      }
    }
}

// ---------------------------------------------------------------------------
// window / offset projection + rmsnorm(H=8) + sigmoid/tanh + x fp16 copy.
// Blocks 512..639: fp16 conversion of kernel_w | v_w | out_w.
// ---------------------------------------------------------------------------
__global__ __launch_bounds__(256) void winoff_kernel(
    const float* __restrict__ x,
    const float* __restrict__ window_w, const float* __restrict__ window_b,
    const float* __restrict__ window_g,
    const float* __restrict__ offset_w, const float* __restrict__ offset_b,
    const float* __restrict__ offset_g,
    float* __restrict__ halfwin, float* __restrict__ cenoff,
    ushort* __restrict__ xh,
    const float* __restrict__ kernel_w, const float* __restrict__ v_w,
    const float* __restrict__ out_w,
    ushort* __restrict__ wkv_h, ushort* __restrict__ ow16)
{
  const int t = threadIdx.x;
  if (blockIdx.x >= 512) {           // weight conversion side-job
    for (int i = (blockIdx.x - 512) * 256 + t; i < 196608; i += 32768) {
      float4 v;
      if (i < 65536)       v = ((const float4*)kernel_w)[i];
      else if (i < 131072) v = ((const float4*)v_w)[i - 65536];
      else                 v = ((const float4*)out_w)[i - 131072];
      ushort4 o = {f2h(v.x), f2h(v.y), f2h(v.z), f2h(v.w)};
      if (i < 131072) ((ushort4*)wkv_h)[i] = o;
      else            ((ushort4*)ow16)[i - 131072] = o;
    }
    return;
  }
  __shared__ float wsm[16][512];   // rows 0..7 window_w, 8..15 offset_w
  {
    float4* dst = (float4*)&wsm[0][0];
    for (int i = t; i < 2048; i += 256)
      dst[i] = (i < 1024) ? ((const float4*)window_w)[i] : ((const float4*)offset_w)[i - 1024];
  }
  __syncthreads();
  const int wid = t >> 6, lane = t & 63;
  for (int it = 0; it < 4; it++) {
    const int row = blockIdx.x * 16 + it * 4 + wid;
    const float4* xr4 = (const float4*)(x + (size_t)row * 512);
    float4 a0 = xr4[lane * 2], a1 = xr4[lane * 2 + 1];
    ushort4 h0 = {f2h(a0.x), f2h(a0.y), f2h(a0.z), f2h(a0.w)};
    ushort4 h1 = {f2h(a1.x), f2h(a1.y), f2h(a1.z), f2h(a1.w)};
    ((ushort4*)(xh + (size_t)row * 512))[lane * 2]     = h0;
    ((ushort4*)(xh + (size_t)row * 512))[lane * 2 + 1] = h1;
    float s[16];
#pragma unroll
    for (int n = 0; n < 16; n++) {
      const float4* wr = (const float4*)&wsm[n][0];
      float4 w0 = wr[lane * 2], w1 = wr[lane * 2 + 1];
      float p = a0.x * w0.x + a0.y * w0.y + a0.z * w0.z + a0.w * w0.w
              + a1.x * w1.x + a1.y * w1.y + a1.z * w1.z + a1.w * w1.w;
#pragma unroll
      for (int off = 32; off >= 1; off >>= 1) p += __shfl_xor(p, off);
      s[n] = p;
    }
    float ssw = 0.f, sso = 0.f;
#pragma unroll
    for (int h = 0; h < 8; h++) {
      s[h]     += window_b[h]; ssw += s[h] * s[h];
      s[8 + h] += offset_b[h]; sso += s[8 + h] * s[8 + h];
    }
    float rw = rsqrtf(ssw * 0.125f + 1e-6f);
    float ro = rsqrtf(sso * 0.125f + 1e-6f);
    if (lane < 8) {
      float z = window_g[lane] * s[lane] * rw;
      halfwin[(size_t)row * 8 + lane] = fmaxf((1.0f + sigm(z) * 11.0f) * 0.5f, 0.5f);
    } else if (lane < 16) {
      int h = lane - 8;
      float z = offset_g[h] * s[8 + h] * ro;
      float th = 1.f - 2.f / (__expf(2.f * z) + 1.f);
      cenoff[(size_t)row * 8 + h] = th * 12.0f;
    }
  }
}

// ---------------------------------------------------------------------------
// fused rmsnorm+silu + deformable conv: one block = one row (512 thr, 8 waves)
// wave w = head h, lane = d. kn in registers; kn[idx] via __shfl; single
// barrier. Interior rows: bilinear collapses, 14 unconditional batched loads.
// XCD-chunked row swizzle (XCD x owns rows [x*1024, x*1024+1024)).
// ---------------------------------------------------------------------------
__global__ __launch_bounds__(512) void conv_row_kernel(
    const float* __restrict__ halfwin, const float* __restrict__ cenoff,
    const ushort* __restrict__ kact_h, const float* __restrict__ kernel_g,
    const ushort* __restrict__ v_h, ushort* __restrict__ oh_h)
{
  __shared__ float red[8];
  const int bid = blockIdx.x;                       // 8192
  const int row = ((bid & 7) << 10) | (bid >> 3);   // 1024 rows per XCD chunk
  const int t = threadIdx.x, w = t >> 6, lane = t & 63;
  const int b = row >> 12, l = row & 4095;

  // rmsnorm partial (this wave's 64-slice) + cross-wave combine
  float kraw = h2f(kact_h[(size_t)row * 512 + t]);
  float ss = kraw * kraw;
#pragma unroll
  for (int off = 32; off >= 1; off >>= 1) ss += __shfl_xor(ss, off);
  if (lane == 0) red[w] = ss;
  __syncthreads();
  float tot = red[0] + red[1] + red[2] + red[3]
            + red[4] + red[5] + red[6] + red[7];
  float r = rsqrtf(tot * (1.f / 512.f) + 1e-6f);
  float a = kernel_g[t] * kraw * r;
  float kn_l = a * sigm(a);              // this lane's kn[d], head w

  const int gw = row * 8 + w;
  const float hw = halfwin[gw];
  const float co = cenoff[gw];
  const ushort* vbase = v_h + ((size_t)b * 4096) * 512 + w * 64 + lane;

  // weight phase: all lanes compute; only lanes 0..12 meaningful
  const float soff = (float)(lane - 6);
  float rel  = fabsf(soff) / hw;
  float ww   = __expf(-rel * rel);
  float npos = fminf(rel, 1.f) * 63.f;
  int   idxk = min((int)npos, 62);
  float wc   = npos - (float)idxk;
  float kf = __shfl(kn_l, idxk);
  float kc = __shfl(kn_l, idxk + 1);
  float kw = fmaxf(kf * (1.f - wc) + kc * wc, 0.f);
  float nb = (float)l + co + soff;
  float wgt = (lane < 13 && nb >= 0.f && nb < 4096.f) ? (kw + 1.f) * ww : 0.f;
  float pc  = fminf(fmaxf(nb, 0.f), 4094.999f);
  int   pfv = (int)pc;
  float frv = pc - (float)pfv;

  float wsum = wgt;
#pragma unroll
  for (int off = 32; off >= 1; off >>= 1) wsum += __shfl_xor(wsum, off);

  const int base = __builtin_amdgcn_readlane(pfv, 0);
  const bool ok = (lane >= 13) || (pfv == base + lane);
  const bool fast = __all((int)ok) && (base + 13 <= 4095);

  float acc0 = 0.f, acc1 = 0.f;
  if (fast) {
    // collapse bilinear: u[r] = w_r*(1-fr_r) + w_{r-1}*fr_{r-1}
    float wfr = wgt * frv;
    float w1f = wgt - wfr;
    float up  = __shfl_up(wfr, 1);
    float u = (lane < 13 ? w1f : 0.f) + ((lane >= 1 && lane <= 13) ? up : 0.f);
    const ushort* vr = vbase + (size_t)base * 512;
    float xv[14];
#pragma unroll
    for (int rr = 0; rr < 14; rr++) xv[rr] = h2f(vr[(size_t)rr * 512]);
#pragma unroll
    for (int rr = 0; rr < 14; rr += 2) {
      acc0 = fmaf(readlane_f(u, rr),     xv[rr],     acc0);
      acc1 = fmaf(readlane_f(u, rr + 1), xv[rr + 1], acc1);
    }
  } else {
#pragma unroll
    for (int si = 0; si < 13; si++) {
      const float w_s  = readlane_f(wgt, si);
      const float fr_s = readlane_f(frv, si);
      const int   pf_s = __builtin_amdgcn_readlane(pfv, si);
      const int   pcl  = min(pf_s + 1, 4095);
      float v0 = h2f(vbase[(size_t)pf_s * 512]);
      float v1 = h2f(vbase[(size_t)pcl * 512]);
      acc0 = fmaf(w_s, v0 + fr_s * (v1 - v0), acc0);
    }
  }

  float val = (acc0 + acc1) / fmaxf(wsum, 1.f);
  oh_h[(size_t)row * 512 + w * 64 + lane] = f2h(val);
}

// ---------------------------------------------------------------------------
// column partial sums over 64-row chunks, XCD-LOCAL: block blk handles global
// row-chunk g = (blk&7)*16 + (blk>>3) -> reads land in own XCD's L2.
// ---------------------------------------------------------------------------
__global__ __launch_bounds__(256) void colpart_kernel(
    const ushort* __restrict__ oh_h, float* __restrict__ partial)
{
  const int blk = blockIdx.x;               // 128
  const int g = (blk & 7) * 16 + (blk >> 3);  // global 64-row chunk 0..127
  const int t = threadIdx.x;                // cols 2t, 2t+1
  const size_t base = (size_t)g * 64 * 512;
  float s0 = 0.f, s1 = 0.f;
  for (int i = 0; i < 64; i++) {
    uint u = *(const uint*)(oh_h + base + (size_t)i * 512 + t * 2);
    s0 += h2f((ushort)(u & 0xffffu));
    s1 += h2f((ushort)(u >> 16));
  }
  partial[(size_t)g * 512 + t * 2]     = s0;
  partial[(size_t)g * 512 + t * 2 + 1] = s1;
}

// ---------------------------------------------------------------------------
// SE: mean inline + hid = silu(mean @ w1^T); wave per (b,j), 256 waves
// ---------------------------------------------------------------------------
__global__ __launch_bounds__(256) void se_hid_kernel(
    const float* __restrict__ partial, const float* __restrict__ w1,
    float* __restrict__ hid_g)
{
  const int wid = threadIdx.x >> 6, lane = threadIdx.x & 63;
  const int g = blockIdx.x * 4 + wid;       // 0..255
  const int b2 = g >> 7, j = g & 127;
  float4 m0 = {0.f, 0.f, 0.f, 0.f}, m1 = {0.f, 0.f, 0.f, 0.f};
#pragma unroll 8
  for (int ch = 0; ch < 64; ch++) {
    const float4* pr = (const float4*)(partial + (size_t)(b2 * 64 + ch) * 512);
    float4 a0 = pr[lane * 2], a1 = pr[lane * 2 + 1];
    m0.x += a0.x; m0.y += a0.y; m0.z += a0.z; m0.w += a0.w;
    m1.x += a1.x; m1.y += a1.y; m1.z += a1.z; m1.w += a1.w;
  }
  float4 wv0 = ((const float4*)(w1 + (size_t)j * 512))[lane * 2];
  float4 wv1 = ((const float4*)(w1 + (size_t)j * 512))[lane * 2 + 1];
  float p = (wv0.x * m0.x + wv0.y * m0.y + wv0.z * m0.z + wv0.w * m0.w
           + wv1.x * m1.x + wv1.y * m1.y + wv1.z * m1.z + wv1.w * m1.w) * (1.f / 4096.f);
#pragma unroll
  for (int off = 32; off >= 1; off >>= 1) p += __shfl_xor(p, off);
  if (lane == 0) hid_g[g] = p * sigm(p);
}

// ---------------------------------------------------------------------------
// SE stage 3: scale_h = f16(sigmoid(hid @ w2^T))   wave per (b, c) output
// ---------------------------------------------------------------------------
__global__ __launch_bounds__(256) void se_scale_kernel(
    const float* __restrict__ hid_g, const float* __restrict__ w2,
    ushort* __restrict__ scale_h)
{
  const int wid = threadIdx.x >> 6, lane = threadIdx.x & 63;
  const int g = blockIdx.x * 4 + wid;       // 0..1023
  const int b3 = g >> 9, c = g & 511;
  float2 wv = ((const float2*)(w2 + (size_t)c * 128))[lane];
  float2 hv = ((const float2*)(hid_g + b3 * 128))[lane];
  float p = wv.x * hv.x + wv.y * hv.y;
#pragma unroll
  for (int off = 32; off >= 1; off >>= 1) p += __shfl_xor(p, off);
  if (lane == 0) scale_h[g] = f2h(sigm(p));
}

// ---------------------------------------------------------------------------
extern "C" void kernel_launch(void* const* d_in, const int* in_sizes, int n_in,
                              void* d_out, int out_size, void* d_ws, size_t ws_size,
                              hipStream_t stream) {
  const float* x        = (const float*)d_in[0];
  const float* window_w = (const float*)d_in[1];
  const float* window_b = (const float*)d_in[2];
  const float* window_g = (const float*)d_in[3];
  const float* offset_w = (const float*)d_in[4];
  const float* offset_b = (const float*)d_in[5];
  const float* offset_g = (const float*)d_in[6];
  const float* kernel_w = (const float*)d_in[7];
  const float* kernel_b = (const float*)d_in[8];
  const float* kernel_g = (const float*)d_in[9];
  const float* v_w      = (const float*)d_in[10];
  const float* v_b      = (const float*)d_in[11];
  const float* se_w1    = (const float*)d_in[12];
  const float* se_w2    = (const float*)d_in[13];
  const float* out_w    = (const float*)d_in[14];
  float* out = (float*)d_out;
  char* ws   = (char*)d_ws;

  const size_t BLC = (size_t)8192 * 512;
  float* halfwin  = (float*)ws;                       ws += 65536 * 4;
  float* cenoff   = (float*)ws;                       ws += 65536 * 4;
  float* partial  = (float*)ws;                       ws += 128 * 512 * 4;
  float* hid_g    = (float*)ws;                       ws += 256 * 4;
  ushort* scale_h = (ushort*)ws;                      ws += 1024 * 2;
  ushort* xh      = (ushort*)ws;                      ws += BLC * 2;
  ushort* wkv_h   = (ushort*)ws;                      ws += 1024 * 512 * 2;
  ushort* ow16    = (ushort*)ws;                      ws += 512 * 512 * 2;
  ushort* kact_h  = (ushort*)ws;                      ws += BLC * 2;
  ushort* v_h     = (ushort*)ws;                      ws += BLC * 2;
  ushort* oh_h    = (ushort*)ws;                      ws += BLC * 2;

  // 1. window/offset projection + x fp16 copy + weight fp16 conversions
  winoff_kernel<<<640, 256, 0, stream>>>(x, window_w, window_b, window_g,
                                         offset_w, offset_b, offset_g,
                                         halfwin, cenoff, xh,
                                         kernel_w, v_w, out_w,
                                         wkv_h, ow16);
  // 2. kernel + v projections (fused dual fp16 MFMA GEMM over N=1024)
  gemm_mfma<0><<<512, 256, 0, stream>>>(xh, wkv_h, kernel_b, v_b,
                                        kact_h, v_h, nullptr, nullptr);
  // 3. fused rmsnorm+silu + deformable conv
  conv_row_kernel<<<8192, 512, 0, stream>>>(halfwin, cenoff, kact_h, kernel_g,
                                            v_h, oh_h);
  // 4. SE chain: colpart (XCD-local) -> hid (256 waves) -> scale (1024 waves)
  colpart_kernel<<<128, 256, 0, stream>>>(oh_h, partial);
  se_hid_kernel<<<64, 256, 0, stream>>>(partial, se_w1, hid_g);
  se_scale_kernel<<<256, 256, 0, stream>>>(hid_g, se_w2, scale_h);
  // 5. final fp16 MFMA GEMM + silu (A = oh * scale via pk_mul, B = out_w fp16)
  gemm_mfma<1><<<256, 256, 0, stream>>>(oh_h, ow16, nullptr, nullptr,
                                        nullptr, nullptr, out, scale_h);
}

// Round 13
// 82.962 us; speedup vs baseline: 1.6646x; 1.0153x over previous
//
#include <hip/hip_runtime.h>
#include <hip/hip_bf16.h>
#include <cstddef>
#include <cstdint>

// Problem constants (B=2, L=4096, C=512, H=8, K=64, D=64)
// max_window = 12, half_max = 6, S = 13, max_offset = 12.0, hid = 128

typedef _Float16 f16x8 __attribute__((ext_vector_type(8)));
typedef float f32x4 __attribute__((ext_vector_type(4)));

#define AS1 __attribute__((address_space(1)))
#define AS3 __attribute__((address_space(3)))

__device__ __forceinline__ void gload_lds16(const ushort* g, ushort* l) {
  __builtin_amdgcn_global_load_lds((const AS1 uint32_t*)g, (AS3 uint32_t*)l, 16, 0, 0);
}
__device__ __forceinline__ ushort f2h(float x) {
  _Float16 h = (_Float16)x;
  return __builtin_bit_cast(ushort, h);
}
__device__ __forceinline__ float h2f(ushort u) {
  return (float)__builtin_bit_cast(_Float16, u);
}
__device__ __forceinline__ float readlane_f(float v, int l) {
  return __int_as_float(__builtin_amdgcn_readlane(__float_as_int(v), l));
}
__device__ __forceinline__ float sigm(float z) { return 1.f / (1.f + __expf(-z)); }

// ---------------------------------------------------------------------------
// fp16 MFMA GEMM: C[m,n] = sum_k A[m,k] * B[n,k]   (K=512)
// 128xBN tile, BK=64, 4 waves (2x2), XOR-swizzled LDS, XCD-chunked swizzle.
// MODE 0: BN=128, 512 blocks, N=1024 -> cols <512 -> fp16 Ck (+bk),
//         >=512 -> Cv (+bv); A and B staged via global_load_lds.
// MODE 1: BN=64, 512 blocks (2 blocks/CU), N=512; A reg-staged with per-k
//         fp16 scale (scale_h[b*512+k], b=m0>>12); B = out_w fp16;
//         epilogue silu -> fp32 Cf.
// ---------------------------------------------------------------------------
template<int MODE>
__global__ __launch_bounds__(256, 2) void gemm_mfma(
    const ushort* __restrict__ A, const ushort* __restrict__ B,
    const float* __restrict__ bk, const float* __restrict__ bv,
    ushort* __restrict__ Ck, ushort* __restrict__ Cv,
    float* __restrict__ Cf, const ushort* __restrict__ scale_h)
{
  constexpr int BN    = (MODE == 0) ? 128 : 64;   // tile N
  constexpr int NF    = BN / 32;                  // B frags per wave (4 / 2)
  constexpr int WSPAN = BN / 2;                   // per-wave-col span (64 / 32)
  constexpr int NB    = BN / 32;                  // B stage gloads (4 / 2)
  __shared__ ushort smem[8192 + BN * 64];   // A tile 128x64 | B tile BNx64
  const int t = threadIdx.x, wid = t >> 6, l = t & 63;

  const int bid = blockIdx.x;
  const int xcd = bid & 7, idx = bid >> 3;
  const int bx = (xcd << 3) | (idx & 7);
  const int by = idx >> 3;
  const int m0 = bx * 128, n0 = by * BN;

  // staging addresses; global col-block pre-swizzled by row&7
  const int swz = ((t & 7) ^ ((t >> 3) & 7)) * 8;
  const ushort* gsrc[4 + NB];  // MODE0: [0..3] A gloads; both: tail = B gloads
  const ushort* asrc[4];       // MODE1 reg-staged A
  const ushort* sptr = nullptr;
  uint32_t loff[4 + NB];
#pragma unroll
  for (int i = 0; i < 4; i++) {
    loff[i] = (i * 32 + wid * 8) * 64;             // wave-uniform
    if (MODE == 0) gsrc[i] = A + (size_t)(m0 + i * 32 + (t >> 3)) * 512 + swz;
    else           asrc[i] = A + (size_t)(m0 + i * 32 + (t >> 3)) * 512 + swz;
  }
#pragma unroll
  for (int i = 0; i < NB; i++) {
    loff[4 + i] = 8192 + (i * 32 + wid * 8) * 64;
    gsrc[4 + i] = B + (size_t)(n0 + i * 32 + (t >> 3)) * 512 + swz;
  }
  if (MODE == 1) sptr = scale_h + (size_t)(m0 >> 12) * 512 + swz;
  const uint32_t awr = (uint32_t)((t >> 3) * 64 + (t & 7) * 8);  // per-thread A dst

  f32x4 acc[4][NF];
#pragma unroll
  for (int m = 0; m < 4; m++)
#pragma unroll
    for (int n = 0; n < NF; n++) acc[m][n] = (f32x4){0.f, 0.f, 0.f, 0.f};

  const int wr = wid >> 1, wc = wid & 1;
  const int fr = l & 15, fq = l >> 4;

  for (int k0 = 0; k0 < 512; k0 += 64) {
    if constexpr (MODE == 1) {
      f16x8 sv = *(const f16x8*)sptr; sptr += 64;
#pragma unroll
      for (int i = 0; i < 4; i++) {
        f16x8 av = *(const f16x8*)asrc[i]; asrc[i] += 64;
        f16x8 pv = av * sv;                          // v_pk_mul_f16
        *(f16x8*)&smem[i * 32 * 64 + awr] = pv;
      }
#pragma unroll
      for (int i = 0; i < NB; i++) {
        gload_lds16(gsrc[4 + i], &smem[loff[4 + i]]);
        gsrc[4 + i] += 64;
      }
    } else {
#pragma unroll
      for (int j = 0; j < 4 + NB; j++) {
        gload_lds16(gsrc[j], &smem[loff[j]]);
        gsrc[j] += 64;
      }
    }
    __syncthreads();   // tiles resident (drains vmcnt + lgkmcnt)

    f16x8 af[4][2], bf[NF][2];
#pragma unroll
    for (int m = 0; m < 4; m++)
#pragma unroll
      for (int ks = 0; ks < 2; ks++) {
        const int ko = 8 * ((ks * 4 + fq) ^ (fr & 7));   // read-side XOR
        af[m][ks] = *(const f16x8*)&smem[(wr * 64 + m * 16 + fr) * 64 + ko];
      }
#pragma unroll
    for (int n = 0; n < NF; n++)
#pragma unroll
      for (int ks = 0; ks < 2; ks++) {
        const int ko = 8 * ((ks * 4 + fq) ^ (fr & 7));
        bf[n][ks] = *(const f16x8*)&smem[8192 + (wc * WSPAN + n * 16 + fr) * 64 + ko];
      }
#pragma unroll
    for (int ks = 0; ks < 2; ks++)
#pragma unroll
      for (int m = 0; m < 4; m++)
#pragma unroll
        for (int n = 0; n < NF; n++)
          acc[m][n] = __builtin_amdgcn_mfma_f32_16x16x32_f16(af[m][ks], bf[n][ks], acc[m][n], 0, 0, 0);
    __syncthreads();   // reads done before next stage overwrites
  }

  // epilogue: C/D layout col=lane&15, row=(lane>>4)*4+reg
  const int rbase = m0 + wr * 64 + (l >> 4) * 4;
  const int cbase = n0 + wc * WSPAN + (l & 15);
#pragma unroll
  for (int m = 0; m < 4; m++)
#pragma unroll
    for (int n = 0; n < NF; n++) {
      const int c = cbase + n * 16;
#pragma unroll
      for (int j = 0; j < 4; j++) {
        const int r = rbase + m * 16 + j;
        float v = acc[m][n][j];
        if (MODE == 0) {
          if (n0 < 512) Ck[(size_t)r * 512 + c]         = f2h(v + bk[c]);
          else          Cv[(size_t)r * 512 + (c - 512)] = f2h(v + bv[c - 512]);
        } else {
          Cf[(size_t)r * 512 + c] = v * sigm(v);
        }
      }
    }
}

// ---------------------------------------------------------------------------
// window / offset projection + rmsnorm(H=8) + sigmoid/tanh + x fp16 copy.
// Blocks 512..639: fp16 conversion of kernel_w | v_w | out_w.
// ---------------------------------------------------------------------------
__global__ __launch_bounds__(256) void winoff_kernel(
    const float* __restrict__ x,
    const float* __restrict__ window_w, const float* __restrict__ window_b,
    const float* __restrict__ window_g,
    const float* __restrict__ offset_w, const float* __restrict__ offset_b,
    const float* __restrict__ offset_g,
    float* __restrict__ halfwin, float* __restrict__ cenoff,
    ushort* __restrict__ xh,
    const float* __restrict__ kernel_w, const float* __restrict__ v_w,
    const float* __restrict__ out_w,
    ushort* __restrict__ wkv_h, ushort* __restrict__ ow16)
{
  const int t = threadIdx.x;
  if (blockIdx.x >= 512) {           // weight conversion side-job
    for (int i = (blockIdx.x - 512) * 256 + t; i < 196608; i += 32768) {
      float4 v;
      if (i < 65536)       v = ((const float4*)kernel_w)[i];
      else if (i < 131072) v = ((const float4*)v_w)[i - 65536];
      else                 v = ((const float4*)out_w)[i - 131072];
      ushort4 o = {f2h(v.x), f2h(v.y), f2h(v.z), f2h(v.w)};
      if (i < 131072) ((ushort4*)wkv_h)[i] = o;
      else            ((ushort4*)ow16)[i - 131072] = o;
    }
    return;
  }
  __shared__ float wsm[16][512];   // rows 0..7 window_w, 8..15 offset_w
  {
    float4* dst = (float4*)&wsm[0][0];
    for (int i = t; i < 2048; i += 256)
      dst[i] = (i < 1024) ? ((const float4*)window_w)[i] : ((const float4*)offset_w)[i - 1024];
  }
  __syncthreads();
  const int wid = t >> 6, lane = t & 63;
  for (int it = 0; it < 4; it++) {
    const int row = blockIdx.x * 16 + it * 4 + wid;
    const float4* xr4 = (const float4*)(x + (size_t)row * 512);
    float4 a0 = xr4[lane * 2], a1 = xr4[lane * 2 + 1];
    ushort4 h0 = {f2h(a0.x), f2h(a0.y), f2h(a0.z), f2h(a0.w)};
    ushort4 h1 = {f2h(a1.x), f2h(a1.y), f2h(a1.z), f2h(a1.w)};
    ((ushort4*)(xh + (size_t)row * 512))[lane * 2]     = h0;
    ((ushort4*)(xh + (size_t)row * 512))[lane * 2 + 1] = h1;
    float s[16];
#pragma unroll
    for (int n = 0; n < 16; n++) {
      const float4* wr = (const float4*)&wsm[n][0];
      float4 w0 = wr[lane * 2], w1 = wr[lane * 2 + 1];
      float p = a0.x * w0.x + a0.y * w0.y + a0.z * w0.z + a0.w * w0.w
              + a1.x * w1.x + a1.y * w1.y + a1.z * w1.z + a1.w * w1.w;
#pragma unroll
      for (int off = 32; off >= 1; off >>= 1) p += __shfl_xor(p, off);
      s[n] = p;
    }
    float ssw = 0.f, sso = 0.f;
#pragma unroll
    for (int h = 0; h < 8; h++) {
      s[h]     += window_b[h]; ssw += s[h] * s[h];
      s[8 + h] += offset_b[h]; sso += s[8 + h] * s[8 + h];
    }
    float rw = rsqrtf(ssw * 0.125f + 1e-6f);
    float ro = rsqrtf(sso * 0.125f + 1e-6f);
    if (lane < 8) {
      float z = window_g[lane] * s[lane] * rw;
      halfwin[(size_t)row * 8 + lane] = fmaxf((1.0f + sigm(z) * 11.0f) * 0.5f, 0.5f);
    } else if (lane < 16) {
      int h = lane - 8;
      float z = offset_g[h] * s[8 + h] * ro;
      float th = 1.f - 2.f / (__expf(2.f * z) + 1.f);
      cenoff[(size_t)row * 8 + h] = th * 12.0f;
    }
  }
}

// ---------------------------------------------------------------------------
// fused rmsnorm+silu + deformable conv: one block = one row (512 thr, 8 waves)
// wave w = head h, lane = d. kn in registers; kn[idx] via __shfl; single
// barrier. Interior rows: bilinear collapses, 14 unconditional batched loads.
// XCD-chunked row swizzle (XCD x owns rows [x*1024, x*1024+1024)).
// ---------------------------------------------------------------------------
__global__ __launch_bounds__(512) void conv_row_kernel(
    const float* __restrict__ halfwin, const float* __restrict__ cenoff,
    const ushort* __restrict__ kact_h, const float* __restrict__ kernel_g,
    const ushort* __restrict__ v_h, ushort* __restrict__ oh_h)
{
  __shared__ float red[8];
  const int bid = blockIdx.x;                       // 8192
  const int row = ((bid & 7) << 10) | (bid >> 3);   // 1024 rows per XCD chunk
  const int t = threadIdx.x, w = t >> 6, lane = t & 63;
  const int b = row >> 12, l = row & 4095;

  // rmsnorm partial (this wave's 64-slice) + cross-wave combine
  float kraw = h2f(kact_h[(size_t)row * 512 + t]);
  float ss = kraw * kraw;
#pragma unroll
  for (int off = 32; off >= 1; off >>= 1) ss += __shfl_xor(ss, off);
  if (lane == 0) red[w] = ss;
  __syncthreads();
  float tot = red[0] + red[1] + red[2] + red[3]
            + red[4] + red[5] + red[6] + red[7];
  float r = rsqrtf(tot * (1.f / 512.f) + 1e-6f);
  float a = kernel_g[t] * kraw * r;
  float kn_l = a * sigm(a);              // this lane's kn[d], head w

  const int gw = row * 8 + w;
  const float hw = halfwin[gw];
  const float co = cenoff[gw];
  const ushort* vbase = v_h + ((size_t)b * 4096) * 512 + w * 64 + lane;

  // weight phase: all lanes compute; only lanes 0..12 meaningful
  const float soff = (float)(lane - 6);
  float rel  = fabsf(soff) / hw;
  float ww   = __expf(-rel * rel);
  float npos = fminf(rel, 1.f) * 63.f;
  int   idxk = min((int)npos, 62);
  float wc   = npos - (float)idxk;
  float kf = __shfl(kn_l, idxk);
  float kc = __shfl(kn_l, idxk + 1);
  float kw = fmaxf(kf * (1.f - wc) + kc * wc, 0.f);
  float nb = (float)l + co + soff;
  float wgt = (lane < 13 && nb >= 0.f && nb < 4096.f) ? (kw + 1.f) * ww : 0.f;
  float pc  = fminf(fmaxf(nb, 0.f), 4094.999f);
  int   pfv = (int)pc;
  float frv = pc - (float)pfv;

  float wsum = wgt;
#pragma unroll
  for (int off = 32; off >= 1; off >>= 1) wsum += __shfl_xor(wsum, off);

  const int base = __builtin_amdgcn_readlane(pfv, 0);
  const bool ok = (lane >= 13) || (pfv == base + lane);
  const bool fast = __all((int)ok) && (base + 13 <= 4095);

  float acc0 = 0.f, acc1 = 0.f;
  if (fast) {
    // collapse bilinear: u[r] = w_r*(1-fr_r) + w_{r-1}*fr_{r-1}
    float wfr = wgt * frv;
    float w1f = wgt - wfr;
    float up  = __shfl_up(wfr, 1);
    float u = (lane < 13 ? w1f : 0.f) + ((lane >= 1 && lane <= 13) ? up : 0.f);
    const ushort* vr = vbase + (size_t)base * 512;
    float xv[14];
#pragma unroll
    for (int rr = 0; rr < 14; rr++) xv[rr] = h2f(vr[(size_t)rr * 512]);
#pragma unroll
    for (int rr = 0; rr < 14; rr += 2) {
      acc0 = fmaf(readlane_f(u, rr),     xv[rr],     acc0);
      acc1 = fmaf(readlane_f(u, rr + 1), xv[rr + 1], acc1);
    }
  } else {
#pragma unroll
    for (int si = 0; si < 13; si++) {
      const float w_s  = readlane_f(wgt, si);
      const float fr_s = readlane_f(frv, si);
      const int   pf_s = __builtin_amdgcn_readlane(pfv, si);
      const int   pcl  = min(pf_s + 1, 4095);
      float v0 = h2f(vbase[(size_t)pf_s * 512]);
      float v1 = h2f(vbase[(size_t)pcl * 512]);
      acc0 = fmaf(w_s, v0 + fr_s * (v1 - v0), acc0);
    }
  }

  float val = (acc0 + acc1) / fmaxf(wsum, 1.f);
  oh_h[(size_t)row * 512 + w * 64 + lane] = f2h(val);
}

// ---------------------------------------------------------------------------
// column partial sums over 64-row chunks, XCD-LOCAL: block blk handles global
// row-chunk g = (blk&7)*16 + (blk>>3) -> reads land in own XCD's L2.
// ---------------------------------------------------------------------------
__global__ __launch_bounds__(256) void colpart_kernel(
    const ushort* __restrict__ oh_h, float* __restrict__ partial)
{
  const int blk = blockIdx.x;               // 128
  const int g = (blk & 7) * 16 + (blk >> 3);  // global 64-row chunk 0..127
  const int t = threadIdx.x;                // cols 2t, 2t+1
  const size_t base = (size_t)g * 64 * 512;
  float s0 = 0.f, s1 = 0.f;
  for (int i = 0; i < 64; i++) {
    uint u = *(const uint*)(oh_h + base + (size_t)i * 512 + t * 2);
    s0 += h2f((ushort)(u & 0xffffu));
    s1 += h2f((ushort)(u >> 16));
  }
  partial[(size_t)g * 512 + t * 2]     = s0;
  partial[(size_t)g * 512 + t * 2 + 1] = s1;
}

// ---------------------------------------------------------------------------
// SE: mean inline + hid = silu(mean @ w1^T); wave per (b,j), 256 waves
// ---------------------------------------------------------------------------
__global__ __launch_bounds__(256) void se_hid_kernel(
    const float* __restrict__ partial, const float* __restrict__ w1,
    float* __restrict__ hid_g)
{
  const int wid = threadIdx.x >> 6, lane = threadIdx.x & 63;
  const int g = blockIdx.x * 4 + wid;       // 0..255
  const int b2 = g >> 7, j = g & 127;
  float4 m0 = {0.f, 0.f, 0.f, 0.f}, m1 = {0.f, 0.f, 0.f, 0.f};
#pragma unroll 8
  for (int ch = 0; ch < 64; ch++) {
    const float4* pr = (const float4*)(partial + (size_t)(b2 * 64 + ch) * 512);
    float4 a0 = pr[lane * 2], a1 = pr[lane * 2 + 1];
    m0.x += a0.x; m0.y += a0.y; m0.z += a0.z; m0.w += a0.w;
    m1.x += a1.x; m1.y += a1.y; m1.z += a1.z; m1.w += a1.w;
  }
  float4 wv0 = ((const float4*)(w1 + (size_t)j * 512))[lane * 2];
  float4 wv1 = ((const float4*)(w1 + (size_t)j * 512))[lane * 2 + 1];
  float p = (wv0.x * m0.x + wv0.y * m0.y + wv0.z * m0.z + wv0.w * m0.w
           + wv1.x * m1.x + wv1.y * m1.y + wv1.z * m1.z + wv1.w * m1.w) * (1.f / 4096.f);
#pragma unroll
  for (int off = 32; off >= 1; off >>= 1) p += __shfl_xor(p, off);
  if (lane == 0) hid_g[g] = p * sigm(p);
}

// ---------------------------------------------------------------------------
// SE stage 3: scale_h = f16(sigmoid(hid @ w2^T))   wave per (b, c) output
// ---------------------------------------------------------------------------
__global__ __launch_bounds__(256) void se_scale_kernel(
    const float* __restrict__ hid_g, const float* __restrict__ w2,
    ushort* __restrict__ scale_h)
{
  const int wid = threadIdx.x >> 6, lane = threadIdx.x & 63;
  const int g = blockIdx.x * 4 + wid;       // 0..1023
  const int b3 = g >> 9, c = g & 511;
  float2 wv = ((const float2*)(w2 + (size_t)c * 128))[lane];
  float2 hv = ((const float2*)(hid_g + b3 * 128))[lane];
  float p = wv.x * hv.x + wv.y * hv.y;
#pragma unroll
  for (int off = 32; off >= 1; off >>= 1) p += __shfl_xor(p, off);
  if (lane == 0) scale_h[g] = f2h(sigm(p));
}

// ---------------------------------------------------------------------------
extern "C" void kernel_launch(void* const* d_in, const int* in_sizes, int n_in,
                              void* d_out, int out_size, void* d_ws, size_t ws_size,
                              hipStream_t stream) {
  const float* x        = (const float*)d_in[0];
  const float* window_w = (const float*)d_in[1];
  const float* window_b = (const float*)d_in[2];
  const float* window_g = (const float*)d_in[3];
  const float* offset_w = (const float*)d_in[4];
  const float* offset_b = (const float*)d_in[5];
  const float* offset_g = (const float*)d_in[6];
  const float* kernel_w = (const float*)d_in[7];
  const float* kernel_b = (const float*)d_in[8];
  const float* kernel_g = (const float*)d_in[9];
  const float* v_w      = (const float*)d_in[10];
  const float* v_b      = (const float*)d_in[11];
  const float* se_w1    = (const float*)d_in[12];
  const float* se_w2    = (const float*)d_in[13];
  const float* out_w    = (const float*)d_in[14];
  float* out = (float*)d_out;
  char* ws   = (char*)d_ws;

  const size_t BLC = (size_t)8192 * 512;
  float* halfwin  = (float*)ws;                       ws += 65536 * 4;
  float* cenoff   = (float*)ws;                       ws += 65536 * 4;
  float* partial  = (float*)ws;                       ws += 128 * 512 * 4;
  float* hid_g    = (float*)ws;                       ws += 256 * 4;
  ushort* scale_h = (ushort*)ws;                      ws += 1024 * 2;
  ushort* xh      = (ushort*)ws;                      ws += BLC * 2;
  ushort* wkv_h   = (ushort*)ws;                      ws += 1024 * 512 * 2;
  ushort* ow16    = (ushort*)ws;                      ws += 512 * 512 * 2;
  ushort* kact_h  = (ushort*)ws;                      ws += BLC * 2;
  ushort* v_h     = (ushort*)ws;                      ws += BLC * 2;
  ushort* oh_h    = (ushort*)ws;                      ws += BLC * 2;

  // 1. window/offset projection + x fp16 copy + weight fp16 conversions
  winoff_kernel<<<640, 256, 0, stream>>>(x, window_w, window_b, window_g,
                                         offset_w, offset_b, offset_g,
                                         halfwin, cenoff, xh,
                                         kernel_w, v_w, out_w,
                                         wkv_h, ow16);
  // 2. kernel + v projections (fused dual fp16 MFMA GEMM over N=1024)
  gemm_mfma<0><<<512, 256, 0, stream>>>(xh, wkv_h, kernel_b, v_b,
                                        kact_h, v_h, nullptr, nullptr);
  // 3. fused rmsnorm+silu + deformable conv
  conv_row_kernel<<<8192, 512, 0, stream>>>(halfwin, cenoff, kact_h, kernel_g,
                                            v_h, oh_h);
  // 4. SE chain: colpart (XCD-local) -> hid (256 waves) -> scale (1024 waves)
  colpart_kernel<<<128, 256, 0, stream>>>(oh_h, partial);
  se_hid_kernel<<<64, 256, 0, stream>>>(partial, se_w1, hid_g);
  se_scale_kernel<<<256, 256, 0, stream>>>(hid_g, se_w2, scale_h);
  // 5. final fp16 MFMA GEMM + silu (128x64 tiles -> 512 blocks, 2/CU)
  gemm_mfma<1><<<512, 256, 0, stream>>>(oh_h, ow16, nullptr, nullptr,
                                        nullptr, nullptr, out, scale_h);
}